// Round 12
// baseline (466.833 us; speedup 1.0000x reference)
//
#include <hip/hip_runtime.h>
#include <cstdint>

static constexpr int N = 20000;
static constexpr int E = 320000;
static constexpr int R = 8;
static constexpr int H = 4;
static constexpr int C = 256;

using short8 = __attribute__((ext_vector_type(8))) short;
using f32x4  = __attribute__((ext_vector_type(4))) float;
using us4    = __attribute__((ext_vector_type(4))) unsigned short;

__device__ __forceinline__ float lrelu(float x, float s) { return x >= 0.f ? x : s * x; }
__device__ __forceinline__ unsigned short f2bf(float f) {
    unsigned u = __float_as_uint(f);
    unsigned r = (u + 0x7FFFu + ((u >> 16) & 1u)) >> 16;
    return (unsigned short)r;
}
__device__ __forceinline__ float bf2f(unsigned short s) {
    return __uint_as_float(((unsigned)s) << 16);
}

// async global->LDS DMA, 16B per lane; LDS dest is wave-uniform base + lane*16
__device__ __forceinline__ void gl2l16(const unsigned short* g, unsigned short* l) {
    __builtin_amdgcn_global_load_lds(
        (const __attribute__((address_space(1))) unsigned int*)g,
        (__attribute__((address_space(3))) unsigned int*)l, 16, 0, 0);
}

#define WTP 72

// ---- device bodies shared by k_prep sections ----
__device__ __forceinline__ void wconv_body(const float* __restrict__ W,
                                           unsigned short* __restrict__ Wt,
                                           int bid, unsigned short* T) {
    int z = bid >> 4;
    int tile = bid & 15;
    int k0 = (tile >> 2) * 64, n0 = (tile & 3) * 64;
    int t = threadIdx.x;
    const float* Wz = W + ((size_t)z << 16);
    int r = t >> 4;
    int cs = (t & 15) * 4;
#pragma unroll
    for (int rr = 0; rr < 4; ++rr) {
        int k = r + rr * 16;
        float4 v = *(const float4*)(Wz + (size_t)(k0 + k) * 256 + n0 + cs);
        T[(cs + 0) * WTP + k] = f2bf(v.x);
        T[(cs + 1) * WTP + k] = f2bf(v.y);
        T[(cs + 2) * WTP + k] = f2bf(v.z);
        T[(cs + 3) * WTP + k] = f2bf(v.w);
    }
    __syncthreads();
    int n = t >> 2, ck = (t & 3) * 16;
    unsigned short* dst = Wt + ((size_t)z << 16) + (size_t)(n0 + n) * 256 + k0 + ck;
    const unsigned short* srcp = T + n * WTP + ck;
    *(uint4*)(dst) = *(const uint4*)(srcp);
    *(uint4*)(dst + 8) = *(const uint4*)(srcp + 8);
}

__device__ __forceinline__ void wqkb_body(const float* __restrict__ W,
                                          const float* __restrict__ q,
                                          const float* __restrict__ kmat,
                                          unsigned short* __restrict__ wqkb,
                                          int w) {
    int lane = threadIdx.x & 63;
    int r = w >> 8, i = w & 255;
    const float* wr = W + ((size_t)(r * 256 + i)) * 256;
    float4 a = *(const float4*)(wr + lane * 4);
    float aq0 = 0.f, aq1 = 0.f, aq2 = 0.f, aq3 = 0.f;
    float ak0 = 0.f, ak1 = 0.f, ak2 = 0.f, ak3 = 0.f;
    int o = lane * 4;
    const float av[4] = {a.x, a.y, a.z, a.w};
#pragma unroll
    for (int j = 0; j < 4; ++j) {
        float4 qv = *(const float4*)(q + (o + j) * 4);
        float4 kv = *(const float4*)(kmat + (o + j) * 4);
        aq0 += av[j] * qv.x; aq1 += av[j] * qv.y;
        aq2 += av[j] * qv.z; aq3 += av[j] * qv.w;
        ak0 += av[j] * kv.x; ak1 += av[j] * kv.y;
        ak2 += av[j] * kv.z; ak3 += av[j] * kv.w;
    }
#pragma unroll
    for (int d = 1; d < 64; d <<= 1) {
        aq0 += __shfl_xor(aq0, d); aq1 += __shfl_xor(aq1, d);
        aq2 += __shfl_xor(aq2, d); aq3 += __shfl_xor(aq3, d);
        ak0 += __shfl_xor(ak0, d); ak1 += __shfl_xor(ak1, d);
        ak2 += __shfl_xor(ak2, d); ak3 += __shfl_xor(ak3, d);
    }
    if (lane == 0) {
        int nq = r * 4, nk = 32 + r * 4;
        wqkb[(nq + 0) * 256 + i] = f2bf(aq0);
        wqkb[(nq + 1) * 256 + i] = f2bf(aq1);
        wqkb[(nq + 2) * 256 + i] = f2bf(aq2);
        wqkb[(nq + 3) * 256 + i] = f2bf(aq3);
        wqkb[(nk + 0) * 256 + i] = f2bf(ak0);
        wqkb[(nk + 1) * 256 + i] = f2bf(ak1);
        wqkb[(nk + 2) * 256 + i] = f2bf(ak2);
        wqkb[(nk + 3) * 256 + i] = f2bf(ak3);
    }
}

// ---- k_prep: fuses all input-only prep work into 1 dispatch ----
// sections: [0,79) zero-cnt | [79,2579) GCN h1 | [2579,2707) wconv r1w ->wt[0..7]
// | [2707,2835) wconv r2w ->wt2[0..7] | [2835,2851) wconv linw ->wt[8]
// | [2851,3363) wqkb layer1 | [3363,3875) wqkb layer2
// | [3875,3883) zero wqkb1 pad rows 64..127 | [3883,3891) zero wqkb2 pad
__global__ __launch_bounds__(256) void k_prep(
    int* __restrict__ cnt,
    const float* __restrict__ cc0, const float* __restrict__ gw1,
    float* __restrict__ h1buf,
    const float* __restrict__ r1w, const float* __restrict__ r2w,
    const float* __restrict__ linw,
    unsigned short* __restrict__ wt, unsigned short* __restrict__ wt2,
    const float* __restrict__ r1q, const float* __restrict__ r1k,
    unsigned short* __restrict__ wqkb1,
    const float* __restrict__ r2q, const float* __restrict__ r2k,
    unsigned short* __restrict__ wqkb2)
{
    __shared__ unsigned short T[64 * WTP];
    int b = blockIdx.x;
    int t = threadIdx.x;
    if (b < 79) {
        int idx = b * 256 + t;
        if (idx < N) cnt[idx] = 0;
    } else if (b < 2579) {
        int idx = (b - 79) * 256 + t;
        if (idx < N * 32) {
            int n = idx >> 5, f = idx & 31;
            const float* xr = cc0 + n * 4;
            float acc = 0.f;
#pragma unroll
            for (int c = 0; c < 4; ++c) acc += xr[c] * gw1[c * 32 + f];
            h1buf[idx] = acc;
        }
    } else if (b < 2707) {
        wconv_body(r1w, wt, b - 2579, T);
    } else if (b < 2835) {
        wconv_body(r2w, wt2, b - 2707, T);
    } else if (b < 2851) {
        wconv_body(linw, wt + ((size_t)R << 16), b - 2835, T);
    } else if (b < 3363) {
        wqkb_body(r1w, r1q, r1k, wqkb1, ((b - 2851) * 256 + t) >> 6);
    } else if (b < 3875) {
        wqkb_body(r2w, r2q, r2k, wqkb2, ((b - 3363) * 256 + t) >> 6);
    } else if (b < 3883) {
        int idx = (b - 3875) * 256 + t;           // 0..2047, 8 shorts each
        uint4 z4 = {0, 0, 0, 0};
        *(uint4*)(wqkb1 + 64 * 256 + idx * 8) = z4;
    } else {
        int idx = (b - 3883) * 256 + t;
        uint4 z4 = {0, 0, 0, 0};
        *(uint4*)(wqkb2 + 64 * 256 + idx * 8) = z4;
    }
}

// ---------------- CSR build ----------------
__global__ void k_count(const int* __restrict__ ei, int* __restrict__ cnt) {
    int e = blockIdx.x * blockDim.x + threadIdx.x;
    if (e < E) atomicAdd(&cnt[ei[E + e]], 1);
}

__global__ __launch_bounds__(256) void k_scan_a(const int* __restrict__ cnt,
                                                int* __restrict__ loc,
                                                int* __restrict__ bsum) {
    __shared__ int sm[256];
    int t = threadIdx.x;
    int idx = blockIdx.x * 256 + t;
    int v = (idx < N) ? cnt[idx] : 0;
    sm[t] = v;
    __syncthreads();
#pragma unroll
    for (int off = 1; off < 256; off <<= 1) {
        int u = (t >= off) ? sm[t - off] : 0;
        __syncthreads();
        if (t >= off) sm[t] += u;
        __syncthreads();
    }
    if (idx < N) loc[idx] = sm[t] - v;
    if (t == 255) bsum[blockIdx.x] = sm[255];
}

__global__ __launch_bounds__(256) void k_scan_c(const int* __restrict__ cnt,
                                                const int* __restrict__ loc,
                                                const int* __restrict__ bsum,
                                                int* __restrict__ rowptr,
                                                int* __restrict__ cursor,
                                                float* __restrict__ dis) {
    __shared__ int wsum[4];
    __shared__ int smoff;
    int t = threadIdx.x;
    int part = 0;
    for (int j = t; j < blockIdx.x; j += 256) part += bsum[j];
#pragma unroll
    for (int d = 1; d < 64; d <<= 1) part += __shfl_xor(part, d);
    if ((t & 63) == 0) wsum[t >> 6] = part;
    __syncthreads();
    if (t == 0) smoff = wsum[0] + wsum[1] + wsum[2] + wsum[3];
    __syncthreads();
    int base = smoff;
    int idx = blockIdx.x * 256 + t;
    if (idx == 0) rowptr[N] = E;
    if (idx >= N) return;
    int run = base + loc[idx];
    rowptr[idx] = run;
    cursor[idx] = run;
    dis[idx] = rsqrtf((float)cnt[idx] + 1.0f);
}

// csr[i] = { (edge_type<<16)|src , original edge id } -- one 8B write per edge
__global__ void k_scatter(const int* __restrict__ ei, const int* __restrict__ et,
                          int* __restrict__ cursor, int2* __restrict__ csr) {
    int e = blockIdx.x * blockDim.x + threadIdx.x;
    if (e >= E) return;
    int d = ei[E + e];
    int pos = atomicAdd(&cursor[d], 1);
    int2 v = { (et[e] << 16) | ei[e], e };
    csr[pos] = v;
}

// ---------------- GCN ----------------
__global__ void k_agg32(const int* __restrict__ rowptr, const int2* __restrict__ csr,
                        const float* __restrict__ dis, const float* __restrict__ h,
                        const float* __restrict__ b, float* __restrict__ c) {
    int idx = blockIdx.x * blockDim.x + threadIdx.x;
    if (idx >= N * 32) return;
    int d = idx >> 5, f = idx & 31;
    int beg = rowptr[d], end = rowptr[d + 1];
    float acc = 0.f;
    for (int i = beg; i < end; ++i) {
        int s = csr[i].x & 0xFFFF;
        acc += dis[s] * h[s * 32 + f];
    }
    float dd = dis[d];
    c[idx] = dd * acc + dd * dd * h[idx] + b[f];
}

// h2 (bf16) + kg copy into x0/xb0, one dispatch
__global__ void k_h2kg(const float* __restrict__ c1, const float* __restrict__ W,
                       const float* __restrict__ kg, unsigned short* __restrict__ h,
                       float* __restrict__ x0, unsigned short* __restrict__ xb0) {
    int idx = blockIdx.x * blockDim.x + threadIdx.x;
    if (idx >= N * 128) return;
    int n = idx >> 7, f = idx & 127;
    const float* cr = c1 + n * 32;
    float acc = 0.f;
    for (int c = 0; c < 32; ++c) acc += lrelu(cr[c], 0.01f) * W[c * 128 + f];
    h[idx] = f2bf(acc);
    float v = kg[idx];
    x0[n * 256 + f] = v;
    xb0[n * 256 + f] = f2bf(v);
}

__global__ void k_agg128(const int* __restrict__ rowptr, const int2* __restrict__ csr,
                         const float* __restrict__ dis,
                         const unsigned short* __restrict__ h,
                         const float* __restrict__ b, float* __restrict__ x0,
                         unsigned short* __restrict__ xb0) {
    int idx = blockIdx.x * blockDim.x + threadIdx.x;
    if (idx >= N * 128) return;
    int d = idx >> 7, f = idx & 127;
    int beg = rowptr[d], end = rowptr[d + 1];
    float acc = 0.f;
    int i = beg;
    for (; i + 2 <= end; i += 2) {
        int s0 = csr[i].x & 0xFFFF;
        int s1 = csr[i + 1].x & 0xFFFF;
        float d0 = dis[s0], d1 = dis[s1];
        float v0 = bf2f(h[s0 * 128 + f]), v1 = bf2f(h[s1 * 128 + f]);
        acc += d0 * v0 + d1 * v1;
    }
    if (i < end) {
        int s = csr[i].x & 0xFFFF;
        acc += dis[s] * bf2f(h[s * 128 + f]);
    }
    float dd = dis[d];
    float v = dd * acc + dd * dd * bf2f(h[d * 128 + f]) + b[f];
    x0[d * 256 + 128 + f] = v;
    xb0[d * 256 + 128 + f] = f2bf(v);
}

// qn|kn = xb @ wqkb^T via MFMA (K<R fallback path only; fused path does this
// inside gemm_mfma4's qk slice)
#define QP 264
__global__ __launch_bounds__(256) void k_qnkn_mfma(
    const unsigned short* __restrict__ xb, const unsigned short* __restrict__ wqkb,
    float* __restrict__ qn, float* __restrict__ kn)
{
    __shared__ unsigned short Ws[64 * QP];
    int t = threadIdx.x;
    {
        int r = t >> 2, off = (t & 3) * 64;
#pragma unroll
        for (int i = 0; i < 8; ++i)
            *(uint4*)(&Ws[r * QP + off + i * 8]) =
                *(const uint4*)(wqkb + r * 256 + off + i * 8);
    }
    __syncthreads();
    int wave = t >> 6, lane = t & 63;
    int lrow = lane & 15, kq = lane >> 4;
    int mw = blockIdx.x * 64 + wave * 16;
    int gm = mw + lrow;
    int gmc = gm < N ? gm : N - 1;

    f32x4 acc[4];
#pragma unroll
    for (int j = 0; j < 4; ++j) acc[j] = (f32x4){0.f, 0.f, 0.f, 0.f};

    for (int k0 = 0; k0 < 8; ++k0) {
        short8 af = *(const short8*)(xb + (size_t)gmc * 256 + k0 * 32 + kq * 8);
#pragma unroll
        for (int j = 0; j < 4; ++j) {
            short8 bf4 = *(const short8*)(&Ws[(j * 16 + lrow) * QP + k0 * 32 + kq * 8]);
            acc[j] = __builtin_amdgcn_mfma_f32_16x16x32_bf16(bf4, af, acc[j], 0, 0, 0);
        }
    }
    if (gm < N) {
#pragma unroll
        for (int j = 0; j < 4; ++j) {
            int colb = j * 16 + kq * 4;
            float4 v = {acc[j][0], acc[j][1], acc[j][2], acc[j][3]};
            if (colb < 32) *(float4*)(qn + (size_t)gm * 32 + colb) = v;
            else           *(float4*)(kn + (size_t)gm * 32 + (colb - 32)) = v;
        }
    }
}

// wave-per-node softmax (K<R fallback path only)
__global__ void k_soft(const int* __restrict__ rowptr, const int2* __restrict__ csr,
                       const float* __restrict__ qn, const float* __restrict__ kn,
                       float* __restrict__ alpha_csr, float* __restrict__ aout) {
    int wid = (blockIdx.x * blockDim.x + threadIdx.x) >> 6;
    int lane = threadIdx.x & 63;
    if (wid >= N) return;
    int d = wid;
    int beg = rowptr[d], end = rowptr[d + 1];
    if (beg >= end) return;
    int slot = lane >> 2, h = lane & 3;
    int nc = (end - beg + 15) >> 4;
    const float* qrow = qn + d * 32;

    auto rawv = [&](int i) {
        int se = csr[i].x;
        int tt = se >> 16, s = se & 0xFFFF;
        return lrelu(qrow[tt * 4 + h] + kn[s * 32 + tt * 4 + h], 0.2f);
    };

    float av[4];
    float m = -1e30f;
    for (int c = 0; c < nc; ++c) {
        int i = beg + c * 16 + slot;
        float v = (i < end) ? rawv(i) : -1e30f;
        if (c < 4) av[c] = v;
        m = fmaxf(m, v);
    }
    m = fmaxf(m, __shfl_xor(m, 4));
    m = fmaxf(m, __shfl_xor(m, 8));
    m = fmaxf(m, __shfl_xor(m, 16));
    m = fmaxf(m, __shfl_xor(m, 32));

    float sum = 0.f;
    for (int c = 0; c < nc; ++c) {
        int i = beg + c * 16 + slot;
        float ex = 0.f;
        if (i < end) {
            float v = (c < 4) ? av[c] : rawv(i);
            ex = expf(v - m);
        }
        if (c < 4) av[c] = ex;
        sum += ex;
    }
    sum += __shfl_xor(sum, 4);
    sum += __shfl_xor(sum, 8);
    sum += __shfl_xor(sum, 16);
    sum += __shfl_xor(sum, 32);
    float inv = 1.f / sum;

    for (int c = 0; c < nc; ++c) {
        int i = beg + c * 16 + slot;
        if (i < end) {
            float ex = (c < 4) ? av[c] : expf(rawv(i) - m);
            float a = ex * inv;
            alpha_csr[i * 4 + h] = a;
            aout[csr[i].y * 4 + h] = a;
        }
    }
}

// ---- FUSED softmax + message gather (K==R fast path) ----
// 4 waves = 4 nodes; packed csr (one 8B read per edge); 4-deep gather ILP.
__global__ __launch_bounds__(256) void k_soft_gather(
    const int* __restrict__ rowptr, const int2* __restrict__ csr,
    const float* __restrict__ qn, const float* __restrict__ kn,
    const unsigned short* __restrict__ xw,
    const float* __restrict__ bias, float* __restrict__ out,
    unsigned short* __restrict__ xbout, float* __restrict__ aout,
    int first, int act)
{
    int node = blockIdx.x * 4 + (threadIdx.x >> 6);
    if (node >= N) return;
    int lane = threadIdx.x & 63;
    int slot = lane >> 2, h = lane & 3;
    int hsel = lane >> 4;
    int beg = rowptr[node], end = rowptr[node + 1];
    float ax = 0.f, ay = 0.f, az = 0.f, aw = 0.f;
    const unsigned short* xwl = xw + lane * 4;

    if (beg < end) {
        int nc = (end - beg + 15) >> 4;
        const float* qrow = qn + node * 32;
        auto rawv_se = [&](int se) {
            int tt = se >> 16, s = se & 0xFFFF;
            return lrelu(qrow[tt * 4 + h] + kn[s * 32 + tt * 4 + h], 0.2f);
        };

        float av[4]; int2 sev[4];
        float m = -1e30f;
        for (int c = 0; c < nc; ++c) {
            int i = beg + c * 16 + slot;
            float v = -1e30f; int2 ce = {0, 0};
            if (i < end) { ce = csr[i]; v = rawv_se(ce.x); }
            if (c < 4) { av[c] = v; sev[c] = ce; }
            m = fmaxf(m, v);
        }
        m = fmaxf(m, __shfl_xor(m, 4));
        m = fmaxf(m, __shfl_xor(m, 8));
        m = fmaxf(m, __shfl_xor(m, 16));
        m = fmaxf(m, __shfl_xor(m, 32));

        float sum = 0.f;
        for (int c = 0; c < nc; ++c) {
            int i = beg + c * 16 + slot;
            float ex = 0.f;
            if (i < end) {
                float v = (c < 4) ? av[c] : rawv_se(csr[i].x);
                ex = expf(v - m);
            }
            if (c < 4) av[c] = ex;
            sum += ex;
        }
        sum += __shfl_xor(sum, 4);
        sum += __shfl_xor(sum, 8);
        sum += __shfl_xor(sum, 16);
        sum += __shfl_xor(sum, 32);
        float inv = 1.f / sum;

        for (int c = 0; c < nc; ++c) {
            int i = beg + c * 16 + slot;
            float a = 0.f;
            int se = 0;
            if (i < end) {
                float ex; int2 ce;
                if (c < 4) { ex = av[c]; ce = sev[c]; }
                else       { ce = csr[i]; ex = expf(rawv_se(ce.x) - m); }
                a = ex * inv;
                se = ce.x;
                aout[ce.y * 4 + h] = a;
            }
            int ne = end - (beg + c * 16);
            if (ne > 16) ne = 16;
            for (int e = 0; e < ne; e += 4) {
                int rr = ne - e;                       // wave-uniform remaining
                int e1 = (rr > 1) ? e + 1 : e;
                int e2 = (rr > 2) ? e + 2 : e;
                int e3 = (rr > 3) ? e + 3 : e;
                float ag0 = __shfl(a, (e  << 2) | hsel);
                float ag1 = __shfl(a, (e1 << 2) | hsel); if (rr <= 1) ag1 = 0.f;
                float ag2 = __shfl(a, (e2 << 2) | hsel); if (rr <= 2) ag2 = 0.f;
                float ag3 = __shfl(a, (e3 << 2) | hsel); if (rr <= 3) ag3 = 0.f;
                int sg0 = __shfl(se, e  << 2);
                int sg1 = __shfl(se, e1 << 2);
                int sg2 = __shfl(se, e2 << 2);
                int sg3 = __shfl(se, e3 << 2);
                uint2 v0 = *(const uint2*)(xwl + ((size_t)(sg0 >> 16) * N + (sg0 & 0xFFFF)) * 256);
                uint2 v1 = *(const uint2*)(xwl + ((size_t)(sg1 >> 16) * N + (sg1 & 0xFFFF)) * 256);
                uint2 v2 = *(const uint2*)(xwl + ((size_t)(sg2 >> 16) * N + (sg2 & 0xFFFF)) * 256);
                uint2 v3 = *(const uint2*)(xwl + ((size_t)(sg3 >> 16) * N + (sg3 & 0xFFFF)) * 256);
                ax += ag0 * __uint_as_float(v0.x << 16);
                ay += ag0 * __uint_as_float(v0.x & 0xFFFF0000u);
                az += ag0 * __uint_as_float(v0.y << 16);
                aw += ag0 * __uint_as_float(v0.y & 0xFFFF0000u);
                ax += ag1 * __uint_as_float(v1.x << 16);
                ay += ag1 * __uint_as_float(v1.x & 0xFFFF0000u);
                az += ag1 * __uint_as_float(v1.y << 16);
                aw += ag1 * __uint_as_float(v1.y & 0xFFFF0000u);
                ax += ag2 * __uint_as_float(v2.x << 16);
                ay += ag2 * __uint_as_float(v2.x & 0xFFFF0000u);
                az += ag2 * __uint_as_float(v2.y << 16);
                aw += ag2 * __uint_as_float(v2.y & 0xFFFF0000u);
                ax += ag3 * __uint_as_float(v3.x << 16);
                ay += ag3 * __uint_as_float(v3.x & 0xFFFF0000u);
                az += ag3 * __uint_as_float(v3.y << 16);
                aw += ag3 * __uint_as_float(v3.y & 0xFFFF0000u);
            }
        }
    }

    float* o = out + (size_t)node * 256 + lane * 4;
    float vx, vy, vz, vw;
    if (first) {
        float4 b = *(const float4*)(bias + lane * 4);
        vx = ax + b.x; vy = ay + b.y; vz = az + b.z; vw = aw + b.w;
    } else {
        float4 q = *(const float4*)o;
        vx = q.x + ax; vy = q.y + ay; vz = q.z + az; vw = q.w + aw;
    }
    if (act) {
        vx = lrelu(vx, 0.01f); vy = lrelu(vy, 0.01f);
        vz = lrelu(vz, 0.01f); vw = lrelu(vw, 0.01f);
        us4 xv = {f2bf(vx), f2bf(vy), f2bf(vz), f2bf(vw)};
        *(us4*)(xbout + (size_t)node * 256 + lane * 4) = xv;
    }
    float4 v = {vx, vy, vz, vw};
    *(float4*)o = v;
}

// ---------------- bf16 MFMA GEMM: round-9 core + fused q/k slice --------------
// 256 thr = 4 waves; tile 128x128, BK=32; single-buffer LDS; 2 barriers/K-step;
// both-sides XOR swizzle (0 conflicts); swapped MFMA operands -> C^T epilogue.
// Slice map (j in [0, NZ*NT+qk)): j<NZ*NT -> z=j%NZ, nb=j/NZ (bf16 xw slices,
// or z==zlin fp32 lin slice); j==NZ*NT (qks>=0) -> q/k projection slice:
// B = wqkb (128 rows, rows 64..127 zero-pad), nb=0; epilogue writes qn/kn fp32
// (cols 0..63; cols 64..127 discarded).
#define TM 128
#define TN 128
__global__ __launch_bounds__(256) void gemm_mfma4(
    const unsigned short* __restrict__ A, const unsigned short* __restrict__ Bt,
    unsigned short* __restrict__ Cbf, float* __restrict__ Cf,
    const float* __restrict__ bias, const float* __restrict__ bias2,
    const unsigned short* __restrict__ Bqk,
    float* __restrict__ qn, float* __restrict__ kn,
    int M, int NZ, int NT, int MT, int zlin, int qks)
{
    __shared__ unsigned short As[128 * 32];
    __shared__ unsigned short Bs[128 * 32];

    int bi = blockIdx.x;
    int cx = bi & 7;
    int g = bi >> 3;
    int per = NZ * NT + (qks >= 0 ? 1 : 0);
    int mh = g / per;
    int j  = g % per;
    int mt = mh * 8 + cx;
    if (mt >= MT) return;
    bool isqk = (qks >= 0 && j == NZ * NT);
    int z = 0, nb = 0;
    if (!isqk) { z = j % NZ; nb = j / NZ; }
    int m0 = mt * TM;
    int n0 = nb * TN;

    const unsigned short* Bz = isqk ? Bqk : (Bt + ((size_t)z << 16));
    int t = threadIdx.x;
    int wave = t >> 6, lane = t & 63;
    int wr = wave >> 1, wc = wave & 1;
    int lrow = lane & 15, kq = lane >> 4;

    int sr0 = (wave * 2 + 0) * 16 + (lane >> 2);
    int sr1 = (wave * 2 + 1) * 16 + (lane >> 2);
    int sc = (((lane & 3) ^ ((lane >> 3) & 3))) * 8;
    int gm0 = m0 + sr0; if (gm0 >= M) gm0 = M - 1;  // clamp: dup rows never stored
    int gm1 = m0 + sr1; if (gm1 >= M) gm1 = M - 1;
    const unsigned short* gA0 = A + (size_t)gm0 * 256 + sc;
    const unsigned short* gA1 = A + (size_t)gm1 * 256 + sc;
    const unsigned short* gB0 = Bz + (size_t)(n0 + sr0) * 256 + sc;
    const unsigned short* gB1 = Bz + (size_t)(n0 + sr1) * 256 + sc;
    unsigned short* lA0 = &As[(wave * 2 + 0) * 512];
    unsigned short* lA1 = &As[(wave * 2 + 1) * 512];
    unsigned short* lB0 = &Bs[(wave * 2 + 0) * 512];
    unsigned short* lB1 = &Bs[(wave * 2 + 1) * 512];

    int rg = (kq ^ ((lrow >> 1) & 3)) * 8;

    f32x4 acc[4][4];
#pragma unroll
    for (int i = 0; i < 4; ++i)
#pragma unroll
        for (int jj = 0; jj < 4; ++jj) acc[i][jj] = (f32x4){0.f, 0.f, 0.f, 0.f};

    for (int k0 = 0; k0 < 256; k0 += 32) {
        gl2l16(gA0 + k0, lA0);
        gl2l16(gA1 + k0, lA1);
        gl2l16(gB0 + k0, lB0);
        gl2l16(gB1 + k0, lB1);
        __syncthreads();
        short8 af[4], bf4[4];
#pragma unroll
        for (int i = 0; i < 4; ++i)
            af[i] = *(const short8*)(&As[(wr * 64 + i * 16 + lrow) * 32 + rg]);
#pragma unroll
        for (int jj = 0; jj < 4; ++jj)
            bf4[jj] = *(const short8*)(&Bs[(wc * 64 + jj * 16 + lrow) * 32 + rg]);
#pragma unroll
        for (int i = 0; i < 4; ++i)
#pragma unroll
            for (int jj = 0; jj < 4; ++jj)
                acc[i][jj] = __builtin_amdgcn_mfma_f32_16x16x32_bf16(bf4[jj], af[i],
                                                                     acc[i][jj], 0, 0, 0);
        __syncthreads();
    }
    // transposed D: lane -> row gm, 4 consecutive cols gnb..gnb+3
    if (isqk) {
        if (wc == 0) {
#pragma unroll
            for (int i = 0; i < 4; ++i) {
                int gm = m0 + wr * 64 + i * 16 + lrow;
                if (gm >= M) continue;
#pragma unroll
                for (int jj = 0; jj < 4; ++jj) {
                    int gnb = jj * 16 + kq * 4;   // 0..60, never straddles 32
                    float4 v = {acc[i][jj][0], acc[i][jj][1],
                                acc[i][jj][2], acc[i][jj][3]};
                    if (gnb < 32) *(float4*)(qn + (size_t)gm * 32 + gnb) = v;
                    else          *(float4*)(kn + (size_t)gm * 32 + (gnb - 32)) = v;
                }
            }
        }
    } else if (z == zlin) {
#pragma unroll
        for (int i = 0; i < 4; ++i) {
            int gm = m0 + wr * 64 + i * 16 + lrow;
            if (gm >= M) continue;
#pragma unroll
            for (int jj = 0; jj < 4; ++jj) {
                int gnb = n0 + wc * 64 + jj * 16 + kq * 4;
                float4 b1 = *(const float4*)(bias + gnb);
                float4 b2 = *(const float4*)(bias2 + gnb);
                float4 v = {acc[i][jj][0] + b1.x + b2.x,
                            acc[i][jj][1] + b1.y + b2.y,
                            acc[i][jj][2] + b1.z + b2.z,
                            acc[i][jj][3] + b1.w + b2.w};
                *(float4*)(Cf + (size_t)gm * 256 + gnb) = v;
            }
        }
    } else {
#pragma unroll
        for (int i = 0; i < 4; ++i) {
            int gm = m0 + wr * 64 + i * 16 + lrow;
            if (gm >= M) continue;
#pragma unroll
            for (int jj = 0; jj < 4; ++jj) {
                int gnb = n0 + wc * 64 + jj * 16 + kq * 4;
                us4 v = {f2bf(acc[i][jj][0]), f2bf(acc[i][jj][1]),
                         f2bf(acc[i][jj][2]), f2bf(acc[i][jj][3])};
                *(us4*)(Cbf + ((size_t)z * M + gm) * 256 + gnb) = v;
            }
        }
    }
}

// ---------------- message aggregation (K<R fallback path only) ----------------
__global__ __launch_bounds__(256) void k_msg_gather(
    const int* __restrict__ rowptr, const int2* __restrict__ csr,
    const float* __restrict__ alpha_csr, const unsigned short* __restrict__ xw,
    const float* __restrict__ bias, float* __restrict__ out,
    unsigned short* __restrict__ xbout, int r0, int r1, int first, int act) {
    int node = blockIdx.x * 4 + (threadIdx.x >> 6);
    if (node >= N) return;
    int lane = threadIdx.x & 63;
    int hsel = lane >> 4;
    int beg = rowptr[node], end = rowptr[node + 1];
    float ax = 0.f, ay = 0.f, az = 0.f, aw = 0.f;
    const unsigned short* xwl = xw + lane * 4;

    for (int i = beg; i < end; ++i) {
        int se = csr[i].x;
        int tt = se >> 16;
        if (tt >= r0 && tt < r1) {
            int s = se & 0xFFFF;
            float a = alpha_csr[i * 4 + hsel];
            uint2 pv = *(const uint2*)(xwl + ((size_t)(tt - r0) * N + s) * 256);
            ax += a * __uint_as_float(pv.x << 16);
            ay += a * __uint_as_float(pv.x & 0xFFFF0000u);
            az += a * __uint_as_float(pv.y << 16);
            aw += a * __uint_as_float(pv.y & 0xFFFF0000u);
        }
    }

    float* o = out + (size_t)node * 256 + lane * 4;
    float vx, vy, vz, vw;
    if (first) {
        float4 b = *(const float4*)(bias + lane * 4);
        vx = ax + b.x; vy = ay + b.y; vz = az + b.z; vw = aw + b.w;
    } else {
        float4 q = *(const float4*)o;
        vx = q.x + ax; vy = q.y + ay; vz = q.z + az; vw = q.w + aw;
    }
    if (act) {
        vx = lrelu(vx, 0.01f); vy = lrelu(vy, 0.01f);
        vz = lrelu(vz, 0.01f); vw = lrelu(vw, 0.01f);
        us4 xv = {f2bf(vx), f2bf(vy), f2bf(vz), f2bf(vw)};
        *(us4*)(xbout + (size_t)node * 256 + lane * 4) = xv;
    }
    float4 v = {vx, vy, vz, vw};
    *(float4*)o = v;
}

extern "C" void kernel_launch(void* const* d_in, const int* in_sizes, int n_in,
                              void* d_out, int out_size, void* d_ws, size_t ws_size,
                              hipStream_t stream) {
    const float* kg   = (const float*)d_in[0];
    const float* cc0  = (const float*)d_in[1];
    const float* gw1  = (const float*)d_in[2];
    const float* gb1  = (const float*)d_in[3];
    const float* gw2  = (const float*)d_in[4];
    const float* gb2  = (const float*)d_in[5];
    const float* r1w  = (const float*)d_in[6];
    const float* r1q  = (const float*)d_in[7];
    const float* r1k  = (const float*)d_in[8];
    const float* r1b  = (const float*)d_in[9];
    const float* r2w  = (const float*)d_in[10];
    const float* r2q  = (const float*)d_in[11];
    const float* r2k  = (const float*)d_in[12];
    const float* r2b  = (const float*)d_in[13];
    const float* linw = (const float*)d_in[14];
    const float* linb = (const float*)d_in[15];
    const int*   ei   = (const int*)d_in[16];
    const int*   et   = (const int*)d_in[17];

    float* out = (float*)d_out;
    float* a1  = out + (size_t)N * C;
    float* a2  = a1 + (size_t)E * H;

    float* ws = (float*)d_ws;
    size_t off = 0;
    float* dis  = ws + off; off += N;
    float* h1   = ws + off; off += (size_t)N * 32;
    float* c1   = ws + off; off += (size_t)N * 32;
    unsigned short* h2b = (unsigned short*)(ws + off); off += (size_t)N * 64;
    float* x0   = ws + off; off += (size_t)N * C;
    float* hmid = ws + off; off += (size_t)N * C;
    float* qn   = ws + off; off += (size_t)N * R * H;
    float* kn   = ws + off; off += (size_t)N * R * H;
    int* cnt     = (int*)(ws + off); off += N;
    int* rowptr  = (int*)(ws + off); off += N + 1;
    int* cursor  = (int*)(ws + off); off += N;
    int* scanloc = (int*)(ws + off); off += N;
    int* scanbs  = (int*)(ws + off); off += 256;
    int2* csr    = (int2*)(ws + off); off += (size_t)E * 2;
    float* alpha = ws + off; off += (size_t)E * H;
    unsigned short* xb0 = (unsigned short*)(ws + off); off += (size_t)N * 128;
    unsigned short* xb1 = (unsigned short*)(ws + off); off += (size_t)N * 128;
    // wt[0..R-1] = r1w slices; wt[R] = lin weight (contiguous); wt2[0..R-1] = r2w
    unsigned short* wt  = (unsigned short*)(ws + off); off += (size_t)(R + 1) * 32768;
    unsigned short* wt2 = (unsigned short*)(ws + off); off += (size_t)R * 32768;
    unsigned short* wqkb1 = (unsigned short*)(ws + off); off += 16384;  // 128x256
    unsigned short* wqkb2 = (unsigned short*)(ws + off); off += 16384;  // 128x256
    unsigned short* xwb = (unsigned short*)(ws + off);

    size_t fixedB = off * 4;
    int K = R;
    if (ws_size > fixedB) {
        size_t kmax = (ws_size - fixedB) / ((size_t)N * C * 2);
        if (kmax < (size_t)K) K = (int)kmax;
    } else {
        K = 1;
    }
    if (K < 1) K = 1;

    const int B = 256;
    auto cdiv = [](long a, long b) { return (int)((a + b - 1) / b); };
    const int MT = cdiv(N, TM);  // 157 m-tiles
    const int NT = C / TN;       // 2
    const int NB = cdiv(N, 256); // 79 scan blocks

    // ---- fused prep (zero-cnt, GCN h1, W transposes, wqkb + pads) ----
    k_prep<<<3891, 256, 0, stream>>>(cnt, cc0, gw1, h1,
                                     r1w, r2w, linw, wt, wt2,
                                     r1q, r1k, wqkb1, r2q, r2k, wqkb2);

    // ---- CSR build ----
    k_count<<<cdiv(E, B), B, 0, stream>>>(ei, cnt);
    k_scan_a<<<NB, 256, 0, stream>>>(cnt, scanloc, scanbs);
    k_scan_c<<<NB, 256, 0, stream>>>(cnt, scanloc, scanbs, rowptr, cursor, dis);
    k_scatter<<<cdiv(E, B), B, 0, stream>>>(ei, et, cursor, csr);

    // ---- GCN ----
    k_agg32<<<cdiv((long)N * 32, B), B, 0, stream>>>(rowptr, csr, dis, h1, gb1, c1);
    k_h2kg<<<cdiv((long)N * 128, B), B, 0, stream>>>(c1, gw2, kg, h2b, x0, xb0);
    k_agg128<<<cdiv((long)N * 128, B), B, 0, stream>>>(rowptr, csr, dis, h2b,
                                                       gb2, x0, xb0);

    auto rgat = [&](unsigned short* xb, const unsigned short* wqkb_l,
                    const unsigned short* wt_l, const float* b,
                    float* obuf, unsigned short* xbout, float* aout,
                    int first, int act, int lin, float* linout,
                    const float* lb1, const float* lb2) {
        if (K == R) {
            // fused: one gemm = all xw slices + lin slice + q/k slice
            int nz = R + (lin ? 1 : 0);
            int zl = lin ? R : -1;
            int per = nz * NT + 1;
            int gx = 8 * per * cdiv(MT, 8);
            gemm_mfma4<<<gx, 256, 0, stream>>>(xb, wt_l, xwb, linout, lb1, lb2,
                                               wqkb_l, qn, kn,
                                               N, nz, NT, MT, zl, nz * NT);
            k_soft_gather<<<cdiv(N, 4), B, 0, stream>>>(
                rowptr, csr, qn, kn, xwb, b, obuf, xbout, aout, first, act);
        } else {
            k_qnkn_mfma<<<cdiv(N, 64), B, 0, stream>>>(xb, wqkb_l, qn, kn);
            k_soft<<<cdiv((long)N * 64, B), B, 0, stream>>>(rowptr, csr,
                                                            qn, kn, alpha, aout);
            for (int r0 = 0; r0 < R; r0 += K) {
                int kc = (R - r0) < K ? (R - r0) : K;
                int addlin = (lin && (r0 + kc == R)) ? 1 : 0;
                int nz = kc + addlin;
                int zl = addlin ? kc : -1;
                int gx = 8 * nz * NT * cdiv(MT, 8);
                gemm_mfma4<<<gx, 256, 0, stream>>>(xb, wt_l + ((size_t)r0 << 16), xwb,
                                                   linout, lb1, lb2,
                                                   nullptr, nullptr, nullptr,
                                                   N, nz, NT, MT, zl, -1);
                int last = (r0 + kc >= R) ? 1 : 0;
                k_msg_gather<<<cdiv(N, 4), 256, 0, stream>>>(
                    rowptr, csr, alpha, xwb, b, obuf, xbout, r0, r0 + kc,
                    (first && r0 == 0) ? 1 : 0, act && last);
            }
        }
    };

    // layer 1: hmid = r1b + messages (leaky fused, emits xb1 bf16);
    //          merged lin slice writes out = x0@linw + (linb + r2b)
    rgat(xb0, wqkb1, wt, r1b, hmid, xb1, a1, 1, 1,
         1, out, linb, r2b);

    // layer 2: out += messages (bias already folded into linear epilogue)
    rgat(xb1, wqkb2, wt2, r2b, out, nullptr, a2, 0, 0,
         0, nullptr, nullptr, nullptr);
}

// Round 13
// 434.237 us; speedup vs baseline: 1.0751x; 1.0751x over previous
//
#include <hip/hip_runtime.h>
#include <cstdint>

static constexpr int N = 20000;
static constexpr int E = 320000;
static constexpr int R = 8;
static constexpr int H = 4;
static constexpr int C = 256;

using short8 = __attribute__((ext_vector_type(8))) short;
using f32x4  = __attribute__((ext_vector_type(4))) float;
using us4    = __attribute__((ext_vector_type(4))) unsigned short;

__device__ __forceinline__ float lrelu(float x, float s) { return x >= 0.f ? x : s * x; }
__device__ __forceinline__ unsigned short f2bf(float f) {
    unsigned u = __float_as_uint(f);
    unsigned r = (u + 0x7FFFu + ((u >> 16) & 1u)) >> 16;
    return (unsigned short)r;
}
__device__ __forceinline__ float bf2f(unsigned short s) {
    return __uint_as_float(((unsigned)s) << 16);
}

// async global->LDS DMA, 16B per lane; LDS dest is wave-uniform base + lane*16
__device__ __forceinline__ void gl2l16(const unsigned short* g, unsigned short* l) {
    __builtin_amdgcn_global_load_lds(
        (const __attribute__((address_space(1))) unsigned int*)g,
        (__attribute__((address_space(3))) unsigned int*)l, 16, 0, 0);
}

#define WTP 72

// ---- device bodies shared by k_prep sections ----
__device__ __forceinline__ void wconv_body(const float* __restrict__ W,
                                           unsigned short* __restrict__ Wt,
                                           int bid, unsigned short* T) {
    int z = bid >> 4;
    int tile = bid & 15;
    int k0 = (tile >> 2) * 64, n0 = (tile & 3) * 64;
    int t = threadIdx.x;
    const float* Wz = W + ((size_t)z << 16);
    int r = t >> 4;
    int cs = (t & 15) * 4;
#pragma unroll
    for (int rr = 0; rr < 4; ++rr) {
        int k = r + rr * 16;
        float4 v = *(const float4*)(Wz + (size_t)(k0 + k) * 256 + n0 + cs);
        T[(cs + 0) * WTP + k] = f2bf(v.x);
        T[(cs + 1) * WTP + k] = f2bf(v.y);
        T[(cs + 2) * WTP + k] = f2bf(v.z);
        T[(cs + 3) * WTP + k] = f2bf(v.w);
    }
    __syncthreads();
    int n = t >> 2, ck = (t & 3) * 16;
    unsigned short* dst = Wt + ((size_t)z << 16) + (size_t)(n0 + n) * 256 + k0 + ck;
    const unsigned short* srcp = T + n * WTP + ck;
    *(uint4*)(dst) = *(const uint4*)(srcp);
    *(uint4*)(dst + 8) = *(const uint4*)(srcp + 8);
}

__device__ __forceinline__ void wqkb_body(const float* __restrict__ W,
                                          const float* __restrict__ q,
                                          const float* __restrict__ kmat,
                                          unsigned short* __restrict__ wqkb,
                                          int w) {
    int lane = threadIdx.x & 63;
    int r = w >> 8, i = w & 255;
    const float* wr = W + ((size_t)(r * 256 + i)) * 256;
    float4 a = *(const float4*)(wr + lane * 4);
    float aq0 = 0.f, aq1 = 0.f, aq2 = 0.f, aq3 = 0.f;
    float ak0 = 0.f, ak1 = 0.f, ak2 = 0.f, ak3 = 0.f;
    int o = lane * 4;
    const float av[4] = {a.x, a.y, a.z, a.w};
#pragma unroll
    for (int j = 0; j < 4; ++j) {
        float4 qv = *(const float4*)(q + (o + j) * 4);
        float4 kv = *(const float4*)(kmat + (o + j) * 4);
        aq0 += av[j] * qv.x; aq1 += av[j] * qv.y;
        aq2 += av[j] * qv.z; aq3 += av[j] * qv.w;
        ak0 += av[j] * kv.x; ak1 += av[j] * kv.y;
        ak2 += av[j] * kv.z; ak3 += av[j] * kv.w;
    }
#pragma unroll
    for (int d = 1; d < 64; d <<= 1) {
        aq0 += __shfl_xor(aq0, d); aq1 += __shfl_xor(aq1, d);
        aq2 += __shfl_xor(aq2, d); aq3 += __shfl_xor(aq3, d);
        ak0 += __shfl_xor(ak0, d); ak1 += __shfl_xor(ak1, d);
        ak2 += __shfl_xor(ak2, d); ak3 += __shfl_xor(ak3, d);
    }
    if (lane == 0) {
        int nq = r * 4, nk = 32 + r * 4;
        wqkb[(nq + 0) * 256 + i] = f2bf(aq0);
        wqkb[(nq + 1) * 256 + i] = f2bf(aq1);
        wqkb[(nq + 2) * 256 + i] = f2bf(aq2);
        wqkb[(nq + 3) * 256 + i] = f2bf(aq3);
        wqkb[(nk + 0) * 256 + i] = f2bf(ak0);
        wqkb[(nk + 1) * 256 + i] = f2bf(ak1);
        wqkb[(nk + 2) * 256 + i] = f2bf(ak2);
        wqkb[(nk + 3) * 256 + i] = f2bf(ak3);
    }
}

// ---- k_prep: fuses all input-only prep work (7 old dispatches -> 1) ----
// sections: [0,79) zero-cnt | [79,2579) GCN h1 | [2579,2707) wconv r1w ->wt[0..7]
// | [2707,2835) wconv r2w ->wt2[0..7] | [2835,2851) wconv linw ->wt[8]
// | [2851,3363) wqkb layer1 | [3363,3875) wqkb layer2
__global__ __launch_bounds__(256) void k_prep(
    int* __restrict__ cnt,
    const float* __restrict__ cc0, const float* __restrict__ gw1,
    float* __restrict__ h1buf,
    const float* __restrict__ r1w, const float* __restrict__ r2w,
    const float* __restrict__ linw,
    unsigned short* __restrict__ wt, unsigned short* __restrict__ wt2,
    const float* __restrict__ r1q, const float* __restrict__ r1k,
    unsigned short* __restrict__ wqkb1,
    const float* __restrict__ r2q, const float* __restrict__ r2k,
    unsigned short* __restrict__ wqkb2)
{
    __shared__ unsigned short T[64 * WTP];
    int b = blockIdx.x;
    int t = threadIdx.x;
    if (b < 79) {
        int idx = b * 256 + t;
        if (idx < N) cnt[idx] = 0;
    } else if (b < 2579) {
        int idx = (b - 79) * 256 + t;
        if (idx < N * 32) {
            int n = idx >> 5, f = idx & 31;
            const float* xr = cc0 + n * 4;
            float acc = 0.f;
#pragma unroll
            for (int c = 0; c < 4; ++c) acc += xr[c] * gw1[c * 32 + f];
            h1buf[idx] = acc;
        }
    } else if (b < 2707) {
        wconv_body(r1w, wt, b - 2579, T);
    } else if (b < 2835) {
        wconv_body(r2w, wt2, b - 2707, T);
    } else if (b < 2851) {
        wconv_body(linw, wt + ((size_t)R << 16), b - 2835, T);
    } else if (b < 3363) {
        wqkb_body(r1w, r1q, r1k, wqkb1, ((b - 2851) * 256 + t) >> 6);
    } else {
        wqkb_body(r2w, r2q, r2k, wqkb2, ((b - 3363) * 256 + t) >> 6);
    }
}

// ---------------- CSR build ----------------
__global__ void k_count(const int* __restrict__ ei, int* __restrict__ cnt) {
    int e = blockIdx.x * blockDim.x + threadIdx.x;
    if (e < E) atomicAdd(&cnt[ei[E + e]], 1);
}

__global__ __launch_bounds__(256) void k_scan_a(const int* __restrict__ cnt,
                                                int* __restrict__ loc,
                                                int* __restrict__ bsum) {
    __shared__ int sm[256];
    int t = threadIdx.x;
    int idx = blockIdx.x * 256 + t;
    int v = (idx < N) ? cnt[idx] : 0;
    sm[t] = v;
    __syncthreads();
#pragma unroll
    for (int off = 1; off < 256; off <<= 1) {
        int u = (t >= off) ? sm[t - off] : 0;
        __syncthreads();
        if (t >= off) sm[t] += u;
        __syncthreads();
    }
    if (idx < N) loc[idx] = sm[t] - v;
    if (t == 255) bsum[blockIdx.x] = sm[255];
}

__global__ __launch_bounds__(256) void k_scan_c(const int* __restrict__ cnt,
                                                const int* __restrict__ loc,
                                                const int* __restrict__ bsum,
                                                int* __restrict__ rowptr,
                                                int* __restrict__ cursor,
                                                float* __restrict__ dis) {
    __shared__ int wsum[4];
    __shared__ int smoff;
    int t = threadIdx.x;
    int part = 0;
    for (int j = t; j < blockIdx.x; j += 256) part += bsum[j];
#pragma unroll
    for (int d = 1; d < 64; d <<= 1) part += __shfl_xor(part, d);
    if ((t & 63) == 0) wsum[t >> 6] = part;
    __syncthreads();
    if (t == 0) smoff = wsum[0] + wsum[1] + wsum[2] + wsum[3];
    __syncthreads();
    int base = smoff;
    int idx = blockIdx.x * 256 + t;
    if (idx == 0) rowptr[N] = E;
    if (idx >= N) return;
    int run = base + loc[idx];
    rowptr[idx] = run;
    cursor[idx] = run;
    dis[idx] = rsqrtf((float)cnt[idx] + 1.0f);
}

// csr_se packs (edge_type<<16)|src ; csr_eid keeps original edge id
__global__ void k_scatter(const int* __restrict__ ei, const int* __restrict__ et,
                          int* __restrict__ cursor, int* __restrict__ csr_se,
                          int* __restrict__ csr_eid) {
    int e = blockIdx.x * blockDim.x + threadIdx.x;
    if (e >= E) return;
    int d = ei[E + e];
    int pos = atomicAdd(&cursor[d], 1);
    csr_se[pos] = (et[e] << 16) | ei[e];
    csr_eid[pos] = e;
}

// ---------------- GCN ----------------
__global__ void k_agg32(const int* __restrict__ rowptr, const int* __restrict__ csr_se,
                        const float* __restrict__ dis, const float* __restrict__ h,
                        const float* __restrict__ b, float* __restrict__ c) {
    int idx = blockIdx.x * blockDim.x + threadIdx.x;
    if (idx >= N * 32) return;
    int d = idx >> 5, f = idx & 31;
    int beg = rowptr[d], end = rowptr[d + 1];
    float acc = 0.f;
    for (int i = beg; i < end; ++i) {
        int s = csr_se[i] & 0xFFFF;
        acc += dis[s] * h[s * 32 + f];
    }
    float dd = dis[d];
    c[idx] = dd * acc + dd * dd * h[idx] + b[f];
}

// h2 (bf16) + kg copy into x0/xb0, one dispatch
__global__ void k_h2kg(const float* __restrict__ c1, const float* __restrict__ W,
                       const float* __restrict__ kg, unsigned short* __restrict__ h,
                       float* __restrict__ x0, unsigned short* __restrict__ xb0) {
    int idx = blockIdx.x * blockDim.x + threadIdx.x;
    if (idx >= N * 128) return;
    int n = idx >> 7, f = idx & 127;
    const float* cr = c1 + n * 32;
    float acc = 0.f;
    for (int c = 0; c < 32; ++c) acc += lrelu(cr[c], 0.01f) * W[c * 128 + f];
    h[idx] = f2bf(acc);
    float v = kg[idx];
    x0[n * 256 + f] = v;
    xb0[n * 256 + f] = f2bf(v);
}

__global__ void k_agg128(const int* __restrict__ rowptr, const int* __restrict__ csr_se,
                         const float* __restrict__ dis,
                         const unsigned short* __restrict__ h,
                         const float* __restrict__ b, float* __restrict__ x0,
                         unsigned short* __restrict__ xb0) {
    int idx = blockIdx.x * blockDim.x + threadIdx.x;
    if (idx >= N * 128) return;
    int d = idx >> 7, f = idx & 127;
    int beg = rowptr[d], end = rowptr[d + 1];
    float acc = 0.f;
    int i = beg;
    for (; i + 2 <= end; i += 2) {
        int s0 = csr_se[i] & 0xFFFF;
        int s1 = csr_se[i + 1] & 0xFFFF;
        float d0 = dis[s0], d1 = dis[s1];
        float v0 = bf2f(h[s0 * 128 + f]), v1 = bf2f(h[s1 * 128 + f]);
        acc += d0 * v0 + d1 * v1;
    }
    if (i < end) {
        int s = csr_se[i] & 0xFFFF;
        acc += dis[s] * bf2f(h[s * 128 + f]);
    }
    float dd = dis[d];
    float v = dd * acc + dd * dd * bf2f(h[d * 128 + f]) + b[f];
    x0[d * 256 + 128 + f] = v;
    xb0[d * 256 + 128 + f] = f2bf(v);
}

// qn|kn = xb @ wqkb^T via MFMA (swapped operands -> C^T, float4 stores)
#define QP 264
__global__ __launch_bounds__(256) void k_qnkn_mfma(
    const unsigned short* __restrict__ xb, const unsigned short* __restrict__ wqkb,
    float* __restrict__ qn, float* __restrict__ kn)
{
    __shared__ unsigned short Ws[64 * QP];
    int t = threadIdx.x;
    {
        int r = t >> 2, off = (t & 3) * 64;
#pragma unroll
        for (int i = 0; i < 8; ++i)
            *(uint4*)(&Ws[r * QP + off + i * 8]) =
                *(const uint4*)(wqkb + r * 256 + off + i * 8);
    }
    __syncthreads();
    int wave = t >> 6, lane = t & 63;
    int lrow = lane & 15, kq = lane >> 4;
    int mw = blockIdx.x * 64 + wave * 16;
    int gm = mw + lrow;
    int gmc = gm < N ? gm : N - 1;

    f32x4 acc[4];
#pragma unroll
    for (int j = 0; j < 4; ++j) acc[j] = (f32x4){0.f, 0.f, 0.f, 0.f};

    for (int k0 = 0; k0 < 8; ++k0) {
        short8 af = *(const short8*)(xb + (size_t)gmc * 256 + k0 * 32 + kq * 8);
#pragma unroll
        for (int j = 0; j < 4; ++j) {
            short8 bf4 = *(const short8*)(&Ws[(j * 16 + lrow) * QP + k0 * 32 + kq * 8]);
            acc[j] = __builtin_amdgcn_mfma_f32_16x16x32_bf16(bf4, af, acc[j], 0, 0, 0);
        }
    }
    if (gm < N) {
#pragma unroll
        for (int j = 0; j < 4; ++j) {
            int colb = j * 16 + kq * 4;
            float4 v = {acc[j][0], acc[j][1], acc[j][2], acc[j][3]};
            if (colb < 32) *(float4*)(qn + (size_t)gm * 32 + colb) = v;
            else           *(float4*)(kn + (size_t)gm * 32 + (colb - 32)) = v;
        }
    }
}

// wave-per-node softmax (K<R fallback path only)
__global__ void k_soft(const int* __restrict__ rowptr, const int* __restrict__ csr_se,
                       const int* __restrict__ csr_eid,
                       const float* __restrict__ qn, const float* __restrict__ kn,
                       float* __restrict__ alpha_csr, float* __restrict__ aout) {
    int wid = (blockIdx.x * blockDim.x + threadIdx.x) >> 6;
    int lane = threadIdx.x & 63;
    if (wid >= N) return;
    int d = wid;
    int beg = rowptr[d], end = rowptr[d + 1];
    if (beg >= end) return;
    int slot = lane >> 2, h = lane & 3;
    int nc = (end - beg + 15) >> 4;
    const float* qrow = qn + d * 32;

    auto rawv = [&](int i) {
        int se = csr_se[i];
        int tt = se >> 16, s = se & 0xFFFF;
        return lrelu(qrow[tt * 4 + h] + kn[s * 32 + tt * 4 + h], 0.2f);
    };

    float av[4];
    float m = -1e30f;
    for (int c = 0; c < nc; ++c) {
        int i = beg + c * 16 + slot;
        float v = (i < end) ? rawv(i) : -1e30f;
        if (c < 4) av[c] = v;
        m = fmaxf(m, v);
    }
    m = fmaxf(m, __shfl_xor(m, 4));
    m = fmaxf(m, __shfl_xor(m, 8));
    m = fmaxf(m, __shfl_xor(m, 16));
    m = fmaxf(m, __shfl_xor(m, 32));

    float sum = 0.f;
    for (int c = 0; c < nc; ++c) {
        int i = beg + c * 16 + slot;
        float ex = 0.f;
        if (i < end) {
            float v = (c < 4) ? av[c] : rawv(i);
            ex = expf(v - m);
        }
        if (c < 4) av[c] = ex;
        sum += ex;
    }
    sum += __shfl_xor(sum, 4);
    sum += __shfl_xor(sum, 8);
    sum += __shfl_xor(sum, 16);
    sum += __shfl_xor(sum, 32);
    float inv = 1.f / sum;

    for (int c = 0; c < nc; ++c) {
        int i = beg + c * 16 + slot;
        if (i < end) {
            float ex = (c < 4) ? av[c] : expf(rawv(i) - m);
            float a = ex * inv;
            alpha_csr[i * 4 + h] = a;
            aout[csr_eid[i] * 4 + h] = a;
        }
    }
}

// ---- FUSED softmax + message gather (K==R fast path) ----
// 4 waves = 4 nodes. Softmax: slot(16) x head(4) shuffle reductions; sev[4]
// caches csr_se from the max pass. Gather: 4-edge batches -> 4 independent
// 8B loads in flight per lane (breaks the 1-deep shfl->load->FMA chain).
__global__ __launch_bounds__(256) void k_soft_gather(
    const int* __restrict__ rowptr, const int* __restrict__ csr_se,
    const int* __restrict__ csr_eid,
    const float* __restrict__ qn, const float* __restrict__ kn,
    const unsigned short* __restrict__ xw,
    const float* __restrict__ bias, float* __restrict__ out,
    unsigned short* __restrict__ xbout, float* __restrict__ aout,
    int first, int act)
{
    int node = blockIdx.x * 4 + (threadIdx.x >> 6);
    if (node >= N) return;
    int lane = threadIdx.x & 63;
    int slot = lane >> 2, h = lane & 3;
    int hsel = lane >> 4;
    int beg = rowptr[node], end = rowptr[node + 1];
    float ax = 0.f, ay = 0.f, az = 0.f, aw = 0.f;
    const unsigned short* xwl = xw + lane * 4;

    if (beg < end) {
        int nc = (end - beg + 15) >> 4;
        const float* qrow = qn + node * 32;
        auto rawv_se = [&](int se) {
            int tt = se >> 16, s = se & 0xFFFF;
            return lrelu(qrow[tt * 4 + h] + kn[s * 32 + tt * 4 + h], 0.2f);
        };

        float av[4]; int sev[4];
        float m = -1e30f;
        for (int c = 0; c < nc; ++c) {
            int i = beg + c * 16 + slot;
            float v = -1e30f; int se = 0;
            if (i < end) { se = csr_se[i]; v = rawv_se(se); }
            if (c < 4) { av[c] = v; sev[c] = se; }
            m = fmaxf(m, v);
        }
        m = fmaxf(m, __shfl_xor(m, 4));
        m = fmaxf(m, __shfl_xor(m, 8));
        m = fmaxf(m, __shfl_xor(m, 16));
        m = fmaxf(m, __shfl_xor(m, 32));

        float sum = 0.f;
        for (int c = 0; c < nc; ++c) {
            int i = beg + c * 16 + slot;
            float ex = 0.f;
            if (i < end) {
                float v = (c < 4) ? av[c] : rawv_se(csr_se[i]);
                ex = expf(v - m);
            }
            if (c < 4) av[c] = ex;
            sum += ex;
        }
        sum += __shfl_xor(sum, 4);
        sum += __shfl_xor(sum, 8);
        sum += __shfl_xor(sum, 16);
        sum += __shfl_xor(sum, 32);
        float inv = 1.f / sum;

        for (int c = 0; c < nc; ++c) {
            int i = beg + c * 16 + slot;
            float a = 0.f;
            int se = 0;
            if (i < end) {
                float ex;
                if (c < 4) { ex = av[c]; se = sev[c]; }
                else       { se = csr_se[i]; ex = expf(rawv_se(se) - m); }
                a = ex * inv;
                aout[csr_eid[i] * 4 + h] = a;
            }
            int ne = end - (beg + c * 16);
            if (ne > 16) ne = 16;
            for (int e = 0; e < ne; e += 4) {
                int rr = ne - e;                       // wave-uniform remaining
                int e1 = (rr > 1) ? e + 1 : e;
                int e2 = (rr > 2) ? e + 2 : e;
                int e3 = (rr > 3) ? e + 3 : e;
                float ag0 = __shfl(a, (e  << 2) | hsel);
                float ag1 = __shfl(a, (e1 << 2) | hsel); if (rr <= 1) ag1 = 0.f;
                float ag2 = __shfl(a, (e2 << 2) | hsel); if (rr <= 2) ag2 = 0.f;
                float ag3 = __shfl(a, (e3 << 2) | hsel); if (rr <= 3) ag3 = 0.f;
                int sg0 = __shfl(se, e  << 2);
                int sg1 = __shfl(se, e1 << 2);
                int sg2 = __shfl(se, e2 << 2);
                int sg3 = __shfl(se, e3 << 2);
                uint2 v0 = *(const uint2*)(xwl + ((size_t)(sg0 >> 16) * N + (sg0 & 0xFFFF)) * 256);
                uint2 v1 = *(const uint2*)(xwl + ((size_t)(sg1 >> 16) * N + (sg1 & 0xFFFF)) * 256);
                uint2 v2 = *(const uint2*)(xwl + ((size_t)(sg2 >> 16) * N + (sg2 & 0xFFFF)) * 256);
                uint2 v3 = *(const uint2*)(xwl + ((size_t)(sg3 >> 16) * N + (sg3 & 0xFFFF)) * 256);
                ax += ag0 * __uint_as_float(v0.x << 16);
                ay += ag0 * __uint_as_float(v0.x & 0xFFFF0000u);
                az += ag0 * __uint_as_float(v0.y << 16);
                aw += ag0 * __uint_as_float(v0.y & 0xFFFF0000u);
                ax += ag1 * __uint_as_float(v1.x << 16);
                ay += ag1 * __uint_as_float(v1.x & 0xFFFF0000u);
                az += ag1 * __uint_as_float(v1.y << 16);
                aw += ag1 * __uint_as_float(v1.y & 0xFFFF0000u);
                ax += ag2 * __uint_as_float(v2.x << 16);
                ay += ag2 * __uint_as_float(v2.x & 0xFFFF0000u);
                az += ag2 * __uint_as_float(v2.y << 16);
                aw += ag2 * __uint_as_float(v2.y & 0xFFFF0000u);
                ax += ag3 * __uint_as_float(v3.x << 16);
                ay += ag3 * __uint_as_float(v3.x & 0xFFFF0000u);
                az += ag3 * __uint_as_float(v3.y << 16);
                aw += ag3 * __uint_as_float(v3.y & 0xFFFF0000u);
            }
        }
    }

    float* o = out + (size_t)node * 256 + lane * 4;
    float vx, vy, vz, vw;
    if (first) {
        float4 b = *(const float4*)(bias + lane * 4);
        vx = ax + b.x; vy = ay + b.y; vz = az + b.z; vw = aw + b.w;
    } else {
        float4 q = *(const float4*)o;
        vx = q.x + ax; vy = q.y + ay; vz = q.z + az; vw = q.w + aw;
    }
    if (act) {
        vx = lrelu(vx, 0.01f); vy = lrelu(vy, 0.01f);
        vz = lrelu(vz, 0.01f); vw = lrelu(vw, 0.01f);
        us4 xv = {f2bf(vx), f2bf(vy), f2bf(vz), f2bf(vw)};
        *(us4*)(xbout + (size_t)node * 256 + lane * 4) = xv;
    }
    float4 v = {vx, vy, vz, vw};
    *(float4*)o = v;
}

// ---------------- bf16 MFMA GEMM: round-9 core (measured best: ~65.2us) -------
// 256 thr = 4 waves; tile 128x128, BK=32; single-buffer LDS (16KB, ~26% occ);
// global_load_lds(16B) staging, 2 barriers per K-step; XCD-grouped swizzle.
// Both-sides XOR swizzle (0 conflicts); swapped MFMA operands -> C^T -> vector
// us4/float4 stores. GEMM CLOSED: 8 structural variants all land 63-70us.
#define TM 128
#define TN 128
__global__ __launch_bounds__(256) void gemm_mfma4(
    const unsigned short* __restrict__ A, const unsigned short* __restrict__ Bt,
    unsigned short* __restrict__ Cbf, float* __restrict__ Cf,
    const float* __restrict__ bias, const float* __restrict__ bias2,
    int M, int NZ, int NT, int MT, int zlin)
{
    __shared__ unsigned short As[128 * 32];
    __shared__ unsigned short Bs[128 * 32];

    int bi = blockIdx.x;
    int cx = bi & 7;
    int g = bi >> 3;
    int per = NZ * NT;
    int mh = g / per;
    int j  = g % per;
    int mt = mh * 8 + cx;
    if (mt >= MT) return;
    int z  = j % NZ;
    int nb = j / NZ;
    int m0 = mt * TM;
    int n0 = nb * TN;

    const unsigned short* Bz = Bt + ((size_t)z << 16);
    int t = threadIdx.x;
    int wave = t >> 6, lane = t & 63;
    int wr = wave >> 1, wc = wave & 1;
    int lrow = lane & 15, kq = lane >> 4;

    int sr0 = (wave * 2 + 0) * 16 + (lane >> 2);
    int sr1 = (wave * 2 + 1) * 16 + (lane >> 2);
    int sc = (((lane & 3) ^ ((lane >> 3) & 3))) * 8;
    int gm0 = m0 + sr0; if (gm0 >= M) gm0 = M - 1;  // clamp: dup rows never stored
    int gm1 = m0 + sr1; if (gm1 >= M) gm1 = M - 1;
    const unsigned short* gA0 = A + (size_t)gm0 * 256 + sc;
    const unsigned short* gA1 = A + (size_t)gm1 * 256 + sc;
    const unsigned short* gB0 = Bz + (size_t)(n0 + sr0) * 256 + sc;
    const unsigned short* gB1 = Bz + (size_t)(n0 + sr1) * 256 + sc;
    unsigned short* lA0 = &As[(wave * 2 + 0) * 512];
    unsigned short* lA1 = &As[(wave * 2 + 1) * 512];
    unsigned short* lB0 = &Bs[(wave * 2 + 0) * 512];
    unsigned short* lB1 = &Bs[(wave * 2 + 1) * 512];

    int rg = (kq ^ ((lrow >> 1) & 3)) * 8;

    f32x4 acc[4][4];
#pragma unroll
    for (int i = 0; i < 4; ++i)
#pragma unroll
        for (int jj = 0; jj < 4; ++jj) acc[i][jj] = (f32x4){0.f, 0.f, 0.f, 0.f};

    for (int k0 = 0; k0 < 256; k0 += 32) {
        gl2l16(gA0 + k0, lA0);
        gl2l16(gA1 + k0, lA1);
        gl2l16(gB0 + k0, lB0);
        gl2l16(gB1 + k0, lB1);
        __syncthreads();
        short8 af[4], bf4[4];
#pragma unroll
        for (int i = 0; i < 4; ++i)
            af[i] = *(const short8*)(&As[(wr * 64 + i * 16 + lrow) * 32 + rg]);
#pragma unroll
        for (int jj = 0; jj < 4; ++jj)
            bf4[jj] = *(const short8*)(&Bs[(wc * 64 + jj * 16 + lrow) * 32 + rg]);
#pragma unroll
        for (int i = 0; i < 4; ++i)
#pragma unroll
            for (int jj = 0; jj < 4; ++jj)
                acc[i][jj] = __builtin_amdgcn_mfma_f32_16x16x32_bf16(bf4[jj], af[i],
                                                                     acc[i][jj], 0, 0, 0);
        __syncthreads();
    }
    if (z == zlin) {
#pragma unroll
        for (int i = 0; i < 4; ++i) {
            int gm = m0 + wr * 64 + i * 16 + lrow;
            if (gm >= M) continue;
#pragma unroll
            for (int jj = 0; jj < 4; ++jj) {
                int gnb = n0 + wc * 64 + jj * 16 + kq * 4;
                float4 b1 = *(const float4*)(bias + gnb);
                float4 b2 = *(const float4*)(bias2 + gnb);
                float4 v = {acc[i][jj][0] + b1.x + b2.x,
                            acc[i][jj][1] + b1.y + b2.y,
                            acc[i][jj][2] + b1.z + b2.z,
                            acc[i][jj][3] + b1.w + b2.w};
                *(float4*)(Cf + (size_t)gm * 256 + gnb) = v;
            }
        }
    } else {
#pragma unroll
        for (int i = 0; i < 4; ++i) {
            int gm = m0 + wr * 64 + i * 16 + lrow;
            if (gm >= M) continue;
#pragma unroll
            for (int jj = 0; jj < 4; ++jj) {
                int gnb = n0 + wc * 64 + jj * 16 + kq * 4;
                us4 v = {f2bf(acc[i][jj][0]), f2bf(acc[i][jj][1]),
                         f2bf(acc[i][jj][2]), f2bf(acc[i][jj][3])};
                *(us4*)(Cbf + ((size_t)z * M + gm) * 256 + gnb) = v;
            }
        }
    }
}

// ---------------- message aggregation (K<R fallback path only) ----------------
__global__ __launch_bounds__(256) void k_msg_gather(
    const int* __restrict__ rowptr, const int* __restrict__ csr_se,
    const float* __restrict__ alpha_csr, const unsigned short* __restrict__ xw,
    const float* __restrict__ bias, float* __restrict__ out,
    unsigned short* __restrict__ xbout, int r0, int r1, int first, int act) {
    int node = blockIdx.x * 4 + (threadIdx.x >> 6);
    if (node >= N) return;
    int lane = threadIdx.x & 63;
    int hsel = lane >> 4;
    int beg = rowptr[node], end = rowptr[node + 1];
    float ax = 0.f, ay = 0.f, az = 0.f, aw = 0.f;
    const unsigned short* xwl = xw + lane * 4;

    for (int i = beg; i < end; ++i) {
        int se = csr_se[i];
        int tt = se >> 16;
        if (tt >= r0 && tt < r1) {
            int s = se & 0xFFFF;
            float a = alpha_csr[i * 4 + hsel];
            uint2 pv = *(const uint2*)(xwl + ((size_t)(tt - r0) * N + s) * 256);
            ax += a * __uint_as_float(pv.x << 16);
            ay += a * __uint_as_float(pv.x & 0xFFFF0000u);
            az += a * __uint_as_float(pv.y << 16);
            aw += a * __uint_as_float(pv.y & 0xFFFF0000u);
        }
    }

    float* o = out + (size_t)node * 256 + lane * 4;
    float vx, vy, vz, vw;
    if (first) {
        float4 b = *(const float4*)(bias + lane * 4);
        vx = ax + b.x; vy = ay + b.y; vz = az + b.z; vw = aw + b.w;
    } else {
        float4 q = *(const float4*)o;
        vx = q.x + ax; vy = q.y + ay; vz = q.z + az; vw = q.w + aw;
    }
    if (act) {
        vx = lrelu(vx, 0.01f); vy = lrelu(vy, 0.01f);
        vz = lrelu(vz, 0.01f); vw = lrelu(vw, 0.01f);
        us4 xv = {f2bf(vx), f2bf(vy), f2bf(vz), f2bf(vw)};
        *(us4*)(xbout + (size_t)node * 256 + lane * 4) = xv;
    }
    float4 v = {vx, vy, vz, vw};
    *(float4*)o = v;
}

extern "C" void kernel_launch(void* const* d_in, const int* in_sizes, int n_in,
                              void* d_out, int out_size, void* d_ws, size_t ws_size,
                              hipStream_t stream) {
    const float* kg   = (const float*)d_in[0];
    const float* cc0  = (const float*)d_in[1];
    const float* gw1  = (const float*)d_in[2];
    const float* gb1  = (const float*)d_in[3];
    const float* gw2  = (const float*)d_in[4];
    const float* gb2  = (const float*)d_in[5];
    const float* r1w  = (const float*)d_in[6];
    const float* r1q  = (const float*)d_in[7];
    const float* r1k  = (const float*)d_in[8];
    const float* r1b  = (const float*)d_in[9];
    const float* r2w  = (const float*)d_in[10];
    const float* r2q  = (const float*)d_in[11];
    const float* r2k  = (const float*)d_in[12];
    const float* r2b  = (const float*)d_in[13];
    const float* linw = (const float*)d_in[14];
    const float* linb = (const float*)d_in[15];
    const int*   ei   = (const int*)d_in[16];
    const int*   et   = (const int*)d_in[17];

    float* out = (float*)d_out;
    float* a1  = out + (size_t)N * C;
    float* a2  = a1 + (size_t)E * H;

    float* ws = (float*)d_ws;
    size_t off = 0;
    float* dis  = ws + off; off += N;
    float* h1   = ws + off; off += (size_t)N * 32;
    float* c1   = ws + off; off += (size_t)N * 32;
    unsigned short* h2b = (unsigned short*)(ws + off); off += (size_t)N * 64;
    float* x0   = ws + off; off += (size_t)N * C;
    float* hmid = ws + off; off += (size_t)N * C;
    float* qn   = ws + off; off += (size_t)N * R * H;
    float* kn   = ws + off; off += (size_t)N * R * H;
    int* cnt     = (int*)(ws + off); off += N;
    int* rowptr  = (int*)(ws + off); off += N + 1;
    int* cursor  = (int*)(ws + off); off += N;
    int* scanloc = (int*)(ws + off); off += N;
    int* scanbs  = (int*)(ws + off); off += 256;
    int* csr_se  = (int*)(ws + off); off += E;
    int* csr_eid = (int*)(ws + off); off += E;
    float* alpha = ws + off; off += (size_t)E * H;
    unsigned short* xb0 = (unsigned short*)(ws + off); off += (size_t)N * 128;
    unsigned short* xb1 = (unsigned short*)(ws + off); off += (size_t)N * 128;
    // wt[0..R-1] = r1w slices; wt[R] = lin weight (contiguous); wt2[0..R-1] = r2w
    unsigned short* wt  = (unsigned short*)(ws + off); off += (size_t)(R + 1) * 32768;
    unsigned short* wt2 = (unsigned short*)(ws + off); off += (size_t)R * 32768;
    unsigned short* wtl = wt + ((size_t)R << 16);
    unsigned short* wqkb1 = (unsigned short*)(ws + off); off += 8192;
    unsigned short* wqkb2 = (unsigned short*)(ws + off); off += 8192;
    unsigned short* xwb = (unsigned short*)(ws + off);

    size_t fixedB = off * 4;
    int K = R;
    if (ws_size > fixedB) {
        size_t kmax = (ws_size - fixedB) / ((size_t)N * C * 2);
        if (kmax < (size_t)K) K = (int)kmax;
    } else {
        K = 1;
    }
    if (K < 1) K = 1;

    const int B = 256;
    auto cdiv = [](long a, long b) { return (int)((a + b - 1) / b); };
    const int MT = cdiv(N, TM);  // 157 m-tiles
    const int NT = C / TN;       // 2
    const int NB = cdiv(N, 256); // 79 scan blocks

    // ---- fused prep (zero-cnt, GCN h1, all W transposes, both wqkb) ----
    k_prep<<<3875, 256, 0, stream>>>(cnt, cc0, gw1, h1,
                                     r1w, r2w, linw, wt, wt2,
                                     r1q, r1k, wqkb1, r2q, r2k, wqkb2);

    // ---- CSR build ----
    k_count<<<cdiv(E, B), B, 0, stream>>>(ei, cnt);
    k_scan_a<<<NB, 256, 0, stream>>>(cnt, scanloc, scanbs);
    k_scan_c<<<NB, 256, 0, stream>>>(cnt, scanloc, scanbs, rowptr, cursor, dis);
    k_scatter<<<cdiv(E, B), B, 0, stream>>>(ei, et, cursor, csr_se, csr_eid);

    // ---- GCN ----
    k_agg32<<<cdiv((long)N * 32, B), B, 0, stream>>>(rowptr, csr_se, dis, h1, gb1, c1);
    k_h2kg<<<cdiv((long)N * 128, B), B, 0, stream>>>(c1, gw2, kg, h2b, x0, xb0);
    k_agg128<<<cdiv((long)N * 128, B), B, 0, stream>>>(rowptr, csr_se, dis, h2b,
                                                       gb2, x0, xb0);

    auto rgat = [&](unsigned short* xb, const unsigned short* wqkb_l,
                    const unsigned short* wt_l, const float* b,
                    float* obuf, unsigned short* xbout, float* aout,
                    int first, int act, int lin, float* linout,
                    const float* lb1, const float* lb2) {
        k_qnkn_mfma<<<cdiv(N, 64), B, 0, stream>>>(xb, wqkb_l, qn, kn);
        if (K == R) {
            // fused fast path: single gemm over all relations, then soft+gather
            int nz = R + (lin ? 1 : 0);
            int zl = lin ? R : -1;
            int gx = 8 * nz * NT * cdiv(MT, 8);
            gemm_mfma4<<<gx, 256, 0, stream>>>(xb, wt_l, xwb, linout, lb1, lb2,
                                               N, nz, NT, MT, zl);
            k_soft_gather<<<cdiv(N, 4), B, 0, stream>>>(
                rowptr, csr_se, csr_eid, qn, kn, xwb, b, obuf, xbout, aout,
                first, act);
        } else {
            k_soft<<<cdiv((long)N * 64, B), B, 0, stream>>>(rowptr, csr_se, csr_eid,
                                                            qn, kn, alpha, aout);
            for (int r0 = 0; r0 < R; r0 += K) {
                int kc = (R - r0) < K ? (R - r0) : K;
                int addlin = (lin && (r0 + kc == R)) ? 1 : 0;
                int nz = kc + addlin;
                int zl = addlin ? kc : -1;
                int gx = 8 * nz * NT * cdiv(MT, 8);
                gemm_mfma4<<<gx, 256, 0, stream>>>(xb, wt_l + ((size_t)r0 << 16), xwb,
                                                   linout, lb1, lb2,
                                                   N, nz, NT, MT, zl);
                int last = (r0 + kc >= R) ? 1 : 0;
                k_msg_gather<<<cdiv(N, 4), 256, 0, stream>>>(
                    rowptr, csr_se, alpha, xwb, b, obuf, xbout, r0, r0 + kc,
                    (first && r0 == 0) ? 1 : 0, act && last);
            }
        }
    };

    // layer 1: hmid = r1b + messages (leaky fused, emits xb1 bf16);
    //          merged lin slice writes out = x0@linw + (linb + r2b)
    rgat(xb0, wqkb1, wt, r1b, hmid, xb1, a1, 1, 1,
         1, out, linb, r2b);

    // layer 2: out += messages (bias already folded into linear epilogue)
    rgat(xb1, wqkb2, wt2, r2b, out, nullptr, a2, 0, 0,
         0, nullptr, nullptr, nullptr);
}